// Round 3
// baseline (43839.703 us; speedup 1.0000x reference)
//
#include <hip/hip_runtime.h>

#define TT 2048
#define FF 64
#define HH 256

typedef short short8 __attribute__((ext_vector_type(8)));
typedef float f32x4 __attribute__((ext_vector_type(4)));

// ws layout (bytes):
//  [0)        packed weights (ushorts): WhhE@0 WihE@262144 WhhD@327680 WihD@589824 WoutP@655360, total 671744 ushorts
//  [1343488)  flags: 64 x u32  (flags[bb*8+gg])
//  [1343744)  hbuf:  8 bb x 2 parity x 16 rows x 256 units bf16 = 131072 B
#define WS_FLAGS_B 1343488
#define WS_HBUF_B  1343744

__device__ inline unsigned short f2b(float f) {
  unsigned int u = __builtin_bit_cast(unsigned int, f);
  u += 0x7fffu + ((u >> 16) & 1u);
  return (unsigned short)(u >> 16);
}

__device__ inline void pin8(short8 &v) { asm volatile("" : "+v"(v)); }

// pack fragment-linear bf16 weights into ws (same as round 2)
__global__ void prep_kernel(const float* __restrict__ Wih_e, const float* __restrict__ Whh_e,
                            const float* __restrict__ Wih_d, const float* __restrict__ Whh_d,
                            const float* __restrict__ Wout, unsigned short* __restrict__ ws) {
  int idx = blockIdx.x * blockDim.x + threadIdx.x;
  if (idx >= 83968) return;
  const float* src; unsigned short* dst; int q, kdim;
  if (idx < 32768)      { q = idx;         src = Whh_e; dst = ws + 0      + q * 8; kdim = HH; }
  else if (idx < 40960) { q = idx - 32768; src = Wih_e; dst = ws + 262144 + q * 8; kdim = FF; }
  else if (idx < 73728) { q = idx - 40960; src = Whh_d; dst = ws + 327680 + q * 8; kdim = HH; }
  else if (idx < 81920) { q = idx - 73728; src = Wih_d; dst = ws + 589824 + q * 8; kdim = FF; }
  else                  { q = idx - 81920; src = Wout;  dst = ws + 655360 + q * 8; kdim = HH; }
  int ksPerTile = (kdim == HH) ? 8 : 2;
  int per = ksPerTile * 64;
  int tile = q / per, rem = q % per;
  int ks = rem / 64, l = rem % 64;
  int col = tile * 16 + (l & 15);
  int k0 = ks * 32 + (l >> 4) * 8;
#pragma unroll
  for (int e = 0; e < 8; e++) dst[e] = f2b(src[col * kdim + k0 + e]);
}

// zero flags + h exchange buffers (every launch -> graph replays deterministic)
__global__ void init_sync(unsigned* __restrict__ flags, unsigned* __restrict__ hbufw) {
  int i = blockIdx.x * blockDim.x + threadIdx.x;
  if (i < 64) flags[i] = 0u;
  if (i < 32768) hbufw[i] = 0u;
}

// 64 blocks: bb = bid&7 (batch group, = XCD under %8 round-robin), gg = bid>>3 (hidden group).
// Block owns batch rows [16bb,16bb+16) x hidden units [32gg,32gg+32). All weights register-resident.
__global__ __launch_bounds__(512, 4) void lstm_kernel(
    const float* __restrict__ xg, const float* __restrict__ b_e,
    const float* __restrict__ b_d, const float* __restrict__ bout,
    const unsigned short* __restrict__ wsu, float* __restrict__ out,
    unsigned* __restrict__ flags, unsigned short* __restrict__ hb) {
  __shared__ unsigned short zb[16][328];   // z = [h(256)|x(64)] bf16
  __shared__ float gbuf[8][16][16];        // per-tile gate results (f32, exact)
  __shared__ unsigned short wout_lds[4096];// Wout tile gg (gg<4): [8 ks][64 lanes][8]

  const int tid = threadIdx.x;
  const int l = tid & 63, w = tid >> 6;
  const int ln = l & 15, lk = l >> 4;
  const int bb = blockIdx.x & 7, gg = blockIdx.x >> 3;
  const int b0 = bb * 16;

  // wave w computes tile: gate g=w>>1, sub s=w&1 -> global col-tile index
  const int cfull = (w >> 1) * 16 + 2 * gg + (w & 1);
  // activation mapping: thread -> (row ar, unit au) of this block's 16x32 patch
  const int ar = tid >> 5, au = tid & 31;

  if (gg < 4) {  // LDS-resident Wout tile (decoder linear, off critical path)
    const short8* WoutP = (const short8*)(wsu + 655360);
    ((short8*)wout_lds)[tid] = WoutP[gg * 512 + tid];
  }
  float bo_ = (gg < 4) ? bout[16 * gg + ln] : 0.f;

  short8 rWhh[8], rWih[2];  // ALL weights for this wave's tile (40 VGPR), pinned
  float bact[4];
  float creg = 0.f;

  unsigned* myflags = flags + bb * 8;
  const int myflag = bb * 8 + gg;

  const int xr0 = tid >> 5, xf0 = (tid & 31) * 2;
  float xv0 = xg[(size_t)(b0 + xr0) * TT * FF + xf0];
  float xv1 = xg[(size_t)(b0 + xr0) * TT * FF + xf0 + 1];

#pragma unroll 1
  for (int it = 0; it < 2 * TT; ++it) {
    const bool dec = (it >= TT);
    const int t = dec ? (2 * TT - 1 - it) : it;

    if (it == 0 || it == TT) {  // phase: load + PIN resident weights, biases
      const short8* WhhP = (const short8*)(wsu + (dec ? 327680 : 0));
      const short8* WihP = (const short8*)(wsu + (dec ? 589824 : 262144));
      const float* bias = dec ? b_d : b_e;
#pragma unroll
      for (int ks = 0; ks < 8; ks++) { rWhh[ks] = WhhP[(cfull * 8 + ks) * 64 + l]; pin8(rWhh[ks]); }
#pragma unroll
      for (int j = 0; j < 2; j++) { rWih[j] = WihP[(cfull * 2 + j) * 64 + l]; pin8(rWih[j]); }
#pragma unroll
      for (int g = 0; g < 4; g++) bact[g] = bias[g * 256 + 32 * gg + au];
    }

    // 1. wait: all 8 producers of this batch group completed iteration it-1
    if (w == 0) {
      while (true) {
        unsigned v = 0xffffffffu;
        if (l < 8) v = __hip_atomic_load(&myflags[l], __ATOMIC_RELAXED, __HIP_MEMORY_SCOPE_AGENT);
        if ((__ballot(v >= (unsigned)it) & 0xffull) == 0xffull) break;
      }
    }
    __syncthreads();
    __builtin_amdgcn_fence(__ATOMIC_ACQUIRE, "agent");

    // 2. stage h(it) (8KB from L2) + x(t) into zb
    {
      const int par = it & 1;
      const int row = tid >> 5, c8 = (tid & 31) * 8;
      short8 hv = *(const short8*)&hb[((bb * 2 + par) * 16 + row) * 256 + c8];
      *(short8*)&zb[row][c8] = hv;
      zb[xr0][HH + xf0] = f2b(xv0);
      zb[xr0][HH + xf0 + 1] = f2b(xv1);
    }
    __syncthreads();

    // 3. A fragments (full z row per lane-slice)
    short8 afr[10];
#pragma unroll
    for (int ks = 0; ks < 10; ks++) afr[ks] = *(const short8*)&zb[ln][ks * 32 + lk * 8];

    // 4. prefetch next x (hides HBM/L3 latency under MFMA+act)
    {
      int it2 = it + 1;
      if (it2 >= 2 * TT) it2 = 0;
      int t2 = (it2 < TT) ? it2 : (2 * TT - 1 - it2);
      const float* px = &xg[((size_t)(b0 + xr0) * TT + t2) * FF + xf0];
      xv0 = px[0];
      xv1 = px[1];
    }

    // 5. gates GEMM: 10 MFMA, all operands in registers
    f32x4 acc = {0.f, 0.f, 0.f, 0.f};
#pragma unroll
    for (int ks = 0; ks < 8; ks++)
      acc = __builtin_amdgcn_mfma_f32_16x16x32_bf16(afr[ks], rWhh[ks], acc, 0, 0, 0);
    acc = __builtin_amdgcn_mfma_f32_16x16x32_bf16(afr[8], rWih[0], acc, 0, 0, 0);
    acc = __builtin_amdgcn_mfma_f32_16x16x32_bf16(afr[9], rWih[1], acc, 0, 0, 0);

    // decoder output: out[:,t] = h(it) @ Wout^T + bout  (wave 7, gg<4)
    if (dec && w == 7 && gg < 4) {
      f32x4 oa = {0.f, 0.f, 0.f, 0.f};
#pragma unroll
      for (int ks = 0; ks < 8; ks++)
        oa = __builtin_amdgcn_mfma_f32_16x16x32_bf16(afr[ks], ((const short8*)wout_lds)[ks * 64 + l], oa, 0, 0, 0);
#pragma unroll
      for (int r = 0; r < 4; r++)
        out[((size_t)(b0 + lk * 4 + r) * TT + t) * FF + 16 * gg + ln] = oa[r] + bo_;
    }

    // 6. publish gate tile to LDS (f32)
#pragma unroll
    for (int j = 0; j < 4; j++) gbuf[w][lk * 4 + j][ln] = acc[j];
    __syncthreads();

    // 7. activation: recombine 4 gates for (ar, au), update c, write h(it+1) chunk
    {
      const int s = au >> 4, uc = au & 15;
      float gi = gbuf[0 + s][ar][uc] + bact[0];
      float gf = gbuf[2 + s][ar][uc] + bact[1];
      float gG = gbuf[4 + s][ar][uc] + bact[2];
      float go = gbuf[6 + s][ar][uc] + bact[3];
      float si = 1.f / (1.f + __expf(-gi));
      float sf = 1.f / (1.f + __expf(-gf));
      float tg = 1.f - 2.f / (__expf(2.f * gG) + 1.f);
      float so = 1.f / (1.f + __expf(-go));
      float cn = sf * creg + si * tg;
      creg = cn;
      float hn = so * (1.f - 2.f / (__expf(2.f * cn) + 1.f));
      const int par2 = (it + 1) & 1;
      hb[((bb * 2 + par2) * 16 + ar) * 256 + 32 * gg + au] = f2b(hn);
    }

    // 8. release own h-chunk, bump flag
    __builtin_amdgcn_fence(__ATOMIC_RELEASE, "agent");
    __syncthreads();
    if (tid == 0)
      __hip_atomic_store(&flags[myflag], (unsigned)(it + 1), __ATOMIC_RELEASE, __HIP_MEMORY_SCOPE_AGENT);
  }
}

extern "C" void kernel_launch(void* const* d_in, const int* in_sizes, int n_in,
                              void* d_out, int out_size, void* d_ws, size_t ws_size,
                              hipStream_t stream) {
  const float* ts    = (const float*)d_in[0];
  const float* Wih_e = (const float*)d_in[1];
  const float* Whh_e = (const float*)d_in[2];
  const float* b_e   = (const float*)d_in[3];
  const float* Wih_d = (const float*)d_in[4];
  const float* Whh_d = (const float*)d_in[5];
  const float* b_d   = (const float*)d_in[6];
  const float* Wout  = (const float*)d_in[7];
  const float* bout  = (const float*)d_in[8];
  unsigned short* ws = (unsigned short*)d_ws;
  float* out = (float*)d_out;

  unsigned* flags = (unsigned*)((char*)d_ws + WS_FLAGS_B);
  unsigned short* hbuf = (unsigned short*)((char*)d_ws + WS_HBUF_B);

  prep_kernel<<<328, 256, 0, stream>>>(Wih_e, Whh_e, Wih_d, Whh_d, Wout, ws);
  init_sync<<<64, 512, 0, stream>>>(flags, (unsigned*)hbuf);
  lstm_kernel<<<64, 512, 0, stream>>>(ts, b_e, b_d, bout, ws, out, flags, hbuf);
}

// Round 5
// 12686.572 us; speedup vs baseline: 3.4556x; 3.4556x over previous
//
#include <hip/hip_runtime.h>

#define TT 2048
#define FF 64
#define HH 256

typedef short short8 __attribute__((ext_vector_type(8)));
typedef float f32x4 __attribute__((ext_vector_type(4)));
typedef unsigned long long u64t;

// ws layout (bytes):
//  [0)        packed bf16 weights (ushorts): WhhE@0 WihE@262144 WhhD@327680 WihD@589824 WoutP@655360
//  [1343488)  hb: [2 par][8 bb][16 r][4 g][22 j] u64 tagged h-words = 22528*8 = 180224 B
#define WS_HB_B 1343488

__device__ inline unsigned short f2b(float f) {
  unsigned int u = __builtin_bit_cast(unsigned int, f);
  u += 0x7fffu + ((u >> 16) & 1u);
  return (unsigned short)(u >> 16);
}
__device__ inline void pin8(short8 &v) { asm volatile("" : "+v"(v)); }

// decode consumer word m (0..1055) -> hb index, zb row, zb col base, triple j
__device__ inline void decw(int m, int gg, int bb, int &wi, int &r, int &go, int &j) {
  r = m / 66;
  int rem = m - 66 * r;
  int gi = rem / 22;
  j = rem - 22 * gi;
  int g2 = gi + (gi >= gg ? 1 : 0);
  wi = ((bb * 16 + r) * 4 + g2) * 22 + j;
  go = 64 * g2;
}

// pack fragment-linear bf16 weights into ws
__global__ void prep_kernel(const float* __restrict__ Wih_e, const float* __restrict__ Whh_e,
                            const float* __restrict__ Wih_d, const float* __restrict__ Whh_d,
                            const float* __restrict__ Wout, unsigned short* __restrict__ ws) {
  int idx = blockIdx.x * blockDim.x + threadIdx.x;
  if (idx >= 83968) return;
  const float* src; unsigned short* dst; int q, kdim;
  if (idx < 32768)      { q = idx;         src = Whh_e; dst = ws + 0      + q * 8; kdim = HH; }
  else if (idx < 40960) { q = idx - 32768; src = Wih_e; dst = ws + 262144 + q * 8; kdim = FF; }
  else if (idx < 73728) { q = idx - 40960; src = Whh_d; dst = ws + 327680 + q * 8; kdim = HH; }
  else if (idx < 81920) { q = idx - 73728; src = Wih_d; dst = ws + 589824 + q * 8; kdim = FF; }
  else                  { q = idx - 81920; src = Wout;  dst = ws + 655360 + q * 8; kdim = HH; }
  int ksPerTile = (kdim == HH) ? 8 : 2;
  int per = ksPerTile * 64;
  int tile = q / per, rem = q % per;
  int ks = rem / 64, l = rem % 64;
  int col = tile * 16 + (l & 15);
  int k0 = ks * 32 + (l >> 4) * 8;
#pragma unroll
  for (int e = 0; e < 8; e++) dst[e] = f2b(src[col * kdim + k0 + e]);
}

// zero tagged exchange buffer each launch (tag 0 == "h(0) = 0" for free)
__global__ void init_hb(u64t* __restrict__ hb) {
  int i = blockIdx.x * blockDim.x + threadIdx.x;
  if (i < 22528) hb[i] = 0ull;
}

// 32 blocks: bb = bid>>2 (batch group), gg = bid&3 (hidden quarter, 64 units).
// All gate weights register-resident. Fence-free tagged h exchange via agent atomics.
__global__ __launch_bounds__(512, 1) void lstm_kernel(
    const float* __restrict__ xg, const float* __restrict__ b_e,
    const float* __restrict__ b_d, const float* __restrict__ bout,
    const unsigned short* __restrict__ wsu, float* __restrict__ out,
    u64t* __restrict__ hb) {
  __shared__ unsigned short zb[16][328];     // z = [h(256)|x(64)] bf16
  __shared__ float gbuf[16][16][17];         // 16 local tiles, padded rows
  __shared__ unsigned short hrow[16][64];    // this block's h chunk
  __shared__ unsigned short wout_lds[4096];  // Wout tile gg: [8 ks][64 lanes][8]

  const int tid = threadIdx.x;
  const int l = tid & 63, w = tid >> 6;
  const int ln = l & 15, lk = l >> 4;
  const int bb = blockIdx.x >> 2, gg = blockIdx.x & 3;
  const int b0 = bb * 16;

  { const short8* WoutP = (const short8*)(wsu + 655360);
    ((short8*)wout_lds)[tid] = WoutP[gg * 512 + tid]; }
  ((unsigned*)hrow)[tid] = 0u;

  const float bo_ = bout[16 * gg + ln];

  // wave w owns gate g = w>>1, sub-tiles s0, s0+1 of this block's 64 units
  const int g = w >> 1, s0 = (w & 1) * 2;
  const int cg0 = g * 16 + 4 * gg + s0;  // global 16-col tile index
  const int lc0 = g * 4 + s0;            // local gbuf tile index

  const int ar = tid >> 5, u0 = (tid & 31) * 2;  // activation: row ar, units u0,u0+1

  // consumer words: m = tid, tid+512, and tid+1024 for tid<32  (1056 total, FIXED)
  int wiA, rA, goA, jA;  decw(tid, gg, bb, wiA, rA, goA, jA);
  int wiB, rB, goB, jB;  decw(tid + 512, gg, bb, wiB, rB, goB, jB);
  int wiC, rC, goC, jC;
  const bool hasC = (tid < 32);
  decw(hasC ? (tid + 1024) : tid, gg, bb, wiC, rC, goC, jC);

  // producer word: tid<352 packs (row pr, triple pj)
  const int pr = tid / 22, pj = tid - 22 * (tid / 22);
  const int pidx = ((bb * 16 + pr) * 4 + gg) * 22 + pj;

  float creg[2] = {0.f, 0.f};

  const int xr0 = tid >> 5, xf0 = (tid & 31) * 2;
  float xv0 = xg[(size_t)(b0 + xr0) * TT * FF + xf0];
  float xv1 = xg[(size_t)(b0 + xr0) * TT * FF + xf0 + 1];

  __syncthreads();  // hrow zero + wout_lds visible

  for (int ph = 0; ph < 2; ++ph) {
    const short8* WhhP = (const short8*)(wsu + (ph ? 327680 : 0));
    const short8* WihP = (const short8*)(wsu + (ph ? 589824 : 262144));
    const float* bias = ph ? b_d : b_e;

    short8 rW0[10], rW1[10];  // ks0..7 = Whh, ks8..9 = Wih — register-resident
#pragma unroll
    for (int ks = 0; ks < 8; ks++) {
      rW0[ks] = WhhP[(cg0 * 8 + ks) * 64 + l];
      rW1[ks] = WhhP[((cg0 + 1) * 8 + ks) * 64 + l];
    }
    rW0[8] = WihP[(cg0 * 2 + 0) * 64 + l];
    rW0[9] = WihP[(cg0 * 2 + 1) * 64 + l];
    rW1[8] = WihP[((cg0 + 1) * 2 + 0) * 64 + l];
    rW1[9] = WihP[((cg0 + 1) * 2 + 1) * 64 + l];
#pragma unroll
    for (int ks = 0; ks < 10; ks++) { pin8(rW0[ks]); pin8(rW1[ks]); }

    float bact[4][2];
#pragma unroll
    for (int g2 = 0; g2 < 4; g2++) {
      bact[g2][0] = bias[g2 * 256 + 64 * gg + u0];
      bact[g2][1] = bias[g2 * 256 + 64 * gg + u0 + 1];
    }

#pragma unroll 1
    for (int ti = 0; ti < TT; ++ti) {
      const int it = ph * TT + ti;
      const int t = ph ? (TT - 1 - ti) : ti;

      // stage x(t) and own h chunk into zb
      zb[xr0][HH + xf0] = f2b(xv0);
      zb[xr0][HH + xf0 + 1] = f2b(xv1);
      zb[ar][64 * gg + u0] = hrow[ar][u0];
      zb[ar][64 * gg + u0 + 1] = hrow[ar][u0 + 1];

      // spin on peers' tagged words (fence-free), unpack into zb
      {
        const u64t* base = hb + (size_t)(it & 1) * 11264;
        u64t vA = 0, vB = 0, vC = 0;
        bool dA = false, dB = false, dC = !hasC;
        do {
          if (!dA) { vA = __hip_atomic_load(base + wiA, __ATOMIC_RELAXED, __HIP_MEMORY_SCOPE_AGENT);
                     dA = ((int)(vA & 0xffffull) == it); }
          if (!dB) { vB = __hip_atomic_load(base + wiB, __ATOMIC_RELAXED, __HIP_MEMORY_SCOPE_AGENT);
                     dB = ((int)(vB & 0xffffull) == it); }
          if (!dC) { vC = __hip_atomic_load(base + wiC, __ATOMIC_RELAXED, __HIP_MEMORY_SCOPE_AGENT);
                     dC = ((int)(vC & 0xffffull) == it); }
        } while (!(dA && dB && dC));
#pragma unroll
        for (int e = 0; e < 3; e++) {
          int u = 3 * jA + e;
          if (u < 64) zb[rA][goA + u] = (unsigned short)(vA >> (16 + 16 * e));
        }
#pragma unroll
        for (int e = 0; e < 3; e++) {
          int u = 3 * jB + e;
          if (u < 64) zb[rB][goB + u] = (unsigned short)(vB >> (16 + 16 * e));
        }
        if (hasC) {
#pragma unroll
          for (int e = 0; e < 3; e++) {
            int u = 3 * jC + e;
            if (u < 64) zb[rC][goC + u] = (unsigned short)(vC >> (16 + 16 * e));
          }
        }
      }
      __syncthreads();  // B1: full z assembled

      short8 afr[10];
#pragma unroll
      for (int ks = 0; ks < 10; ks++) afr[ks] = *(const short8*)&zb[ln][ks * 32 + lk * 8];

      {  // prefetch next x
        int it2 = it + 1; if (it2 >= 2 * TT) it2 = 0;
        int t2 = (it2 < TT) ? it2 : (2 * TT - 1 - it2);
        const float* px = &xg[((size_t)(b0 + xr0) * TT + t2) * FF + xf0];
        xv0 = px[0]; xv1 = px[1];
      }

      f32x4 acc0 = {0.f, 0.f, 0.f, 0.f}, acc1 = {0.f, 0.f, 0.f, 0.f};
#pragma unroll
      for (int ks = 0; ks < 10; ks++) {
        acc0 = __builtin_amdgcn_mfma_f32_16x16x32_bf16(afr[ks], rW0[ks], acc0, 0, 0, 0);
        acc1 = __builtin_amdgcn_mfma_f32_16x16x32_bf16(afr[ks], rW1[ks], acc1, 0, 0, 0);
      }

      // decoder output (wave 7): out[:,t] = h(it) @ Wout^T + bout, feats 16gg..16gg+16
      if (ph == 1 && w == 7) {
        f32x4 oa = {0.f, 0.f, 0.f, 0.f};
#pragma unroll
        for (int ks = 0; ks < 8; ks++)
          oa = __builtin_amdgcn_mfma_f32_16x16x32_bf16(afr[ks], ((const short8*)wout_lds)[ks * 64 + l], oa, 0, 0, 0);
#pragma unroll
        for (int r = 0; r < 4; r++)
          out[((size_t)(b0 + lk * 4 + r) * TT + t) * FF + 16 * gg + ln] = oa[r] + bo_;
      }

#pragma unroll
      for (int j = 0; j < 4; j++) {
        gbuf[lc0][lk * 4 + j][ln] = acc0[j];
        gbuf[lc0 + 1][lk * 4 + j][ln] = acc1[j];
      }
      __syncthreads();  // B3: gbuf ready

#pragma unroll
      for (int e = 0; e < 2; e++) {
        const int u = u0 + e, ss = u >> 4, uc = u & 15;
        float gi = gbuf[0 + ss][ar][uc] + bact[0][e];
        float gf = gbuf[4 + ss][ar][uc] + bact[1][e];
        float gG = gbuf[8 + ss][ar][uc] + bact[2][e];
        float go = gbuf[12 + ss][ar][uc] + bact[3][e];
        float si = 1.f / (1.f + __expf(-gi));
        float sf = 1.f / (1.f + __expf(-gf));
        float tg = 1.f - 2.f / (__expf(2.f * gG) + 1.f);
        float so = 1.f / (1.f + __expf(-go));
        float cn = sf * creg[e] + si * tg;
        creg[e] = cn;
        float hn = so * (1.f - 2.f / (__expf(2.f * cn) + 1.f));
        hrow[ar][u] = f2b(hn);
      }
      __syncthreads();  // B4: hrow ready, gbuf reads done

      // publish own h(it+1) chunk: tag-embedded u64, relaxed agent atomics, no fence
      if (tid < 352) {
        u64t word = (u64t)(unsigned)(it + 1);
#pragma unroll
        for (int e = 0; e < 3; e++) {
          int u = 3 * pj + e;
          unsigned short hv = (u < 64) ? hrow[pr][u] : (unsigned short)0;
          word |= (u64t)hv << (16 + 16 * e);
        }
        __hip_atomic_store(hb + (size_t)((it + 1) & 1) * 11264 + pidx, word,
                           __ATOMIC_RELAXED, __HIP_MEMORY_SCOPE_AGENT);
      }
    }
  }
}

extern "C" void kernel_launch(void* const* d_in, const int* in_sizes, int n_in,
                              void* d_out, int out_size, void* d_ws, size_t ws_size,
                              hipStream_t stream) {
  const float* ts    = (const float*)d_in[0];
  const float* Wih_e = (const float*)d_in[1];
  const float* Whh_e = (const float*)d_in[2];
  const float* b_e   = (const float*)d_in[3];
  const float* Wih_d = (const float*)d_in[4];
  const float* Whh_d = (const float*)d_in[5];
  const float* b_d   = (const float*)d_in[6];
  const float* Wout  = (const float*)d_in[7];
  const float* bout  = (const float*)d_in[8];
  unsigned short* ws = (unsigned short*)d_ws;
  float* out = (float*)d_out;
  u64t* hb = (u64t*)((char*)d_ws + WS_HB_B);

  prep_kernel<<<328, 256, 0, stream>>>(Wih_e, Whh_e, Wih_d, Whh_d, Wout, ws);
  init_hb<<<44, 512, 0, stream>>>(hb);
  lstm_kernel<<<32, 512, 0, stream>>>(ts, b_e, b_d, bout, ws, out, hb);
}

// Round 6
// 9583.855 us; speedup vs baseline: 4.5743x; 1.3237x over previous
//
#include <hip/hip_runtime.h>

#define TT 2048
#define FF 64
#define HH 256

typedef short short8 __attribute__((ext_vector_type(8)));
typedef float f32x4 __attribute__((ext_vector_type(4)));
typedef unsigned long long u64t;

// ws layout (bytes):
//  [0)        packed bf16 weights (ushorts): WhhE@0 WihE@262144 WhhD@327680 WihD@589824 WoutP@655360
//  [1343488)  hb: [2 par][8 bb][16 r][4 g][32 pair] u64 tagged h-words = 32768*8 = 262144 B
#define WS_HB_B 1343488

__device__ inline unsigned short f2b(float f) {
  unsigned int u = __builtin_bit_cast(unsigned int, f);
  u += 0x7fffu + ((u >> 16) & 1u);
  return (unsigned short)(u >> 16);
}
__device__ inline void pin8(short8 &v) { asm volatile("" : "+v"(v)); }

// pack fragment-linear bf16 weights into ws
__global__ void prep_kernel(const float* __restrict__ Wih_e, const float* __restrict__ Whh_e,
                            const float* __restrict__ Wih_d, const float* __restrict__ Whh_d,
                            const float* __restrict__ Wout, unsigned short* __restrict__ ws) {
  int idx = blockIdx.x * blockDim.x + threadIdx.x;
  if (idx >= 83968) return;
  const float* src; unsigned short* dst; int q, kdim;
  if (idx < 32768)      { q = idx;         src = Whh_e; dst = ws + 0      + q * 8; kdim = HH; }
  else if (idx < 40960) { q = idx - 32768; src = Wih_e; dst = ws + 262144 + q * 8; kdim = FF; }
  else if (idx < 73728) { q = idx - 40960; src = Whh_d; dst = ws + 327680 + q * 8; kdim = HH; }
  else if (idx < 81920) { q = idx - 73728; src = Wih_d; dst = ws + 589824 + q * 8; kdim = FF; }
  else                  { q = idx - 81920; src = Wout;  dst = ws + 655360 + q * 8; kdim = HH; }
  int ksPerTile = (kdim == HH) ? 8 : 2;
  int per = ksPerTile * 64;
  int tile = q / per, rem = q % per;
  int ks = rem / 64, l = rem % 64;
  int col = tile * 16 + (l & 15);
  int k0 = ks * 32 + (l >> 4) * 8;
#pragma unroll
  for (int e = 0; e < 8; e++) dst[e] = f2b(src[col * kdim + k0 + e]);
}

// zero tagged exchange buffer each launch (tag 0 == "h(0) = 0" for free)
__global__ void init_hb(u64t* __restrict__ hb) {
  int i = blockIdx.x * blockDim.x + threadIdx.x;
  if (i < 32768) hb[i] = 0ull;
}

// 32 blocks: bb = bid&7 (batch group -> all 4 peers share an XCD under %8 round-robin),
// gg = bid>>3 (hidden quarter, 64 units). All gate weights register-resident (pinned
// EVERY iteration so the compiler cannot rematerialize). Fence-free tagged h exchange.
__global__ __launch_bounds__(512, 1) void lstm_kernel(
    const float* __restrict__ xg, const float* __restrict__ b_e,
    const float* __restrict__ b_d, const float* __restrict__ bout,
    const unsigned short* __restrict__ wsu, float* __restrict__ out,
    u64t* __restrict__ hb) {
  __shared__ unsigned short zb[16][328];     // z = [h(256)|x(64)] bf16
  __shared__ float gbuf[16][16][17];         // 16 local gate tiles, padded rows
  __shared__ unsigned short wout_lds[4096];  // Wout tile gg: [8 ks][64 lanes][8]

  const int tid = threadIdx.x;
  const int l = tid & 63, w = tid >> 6;
  const int ln = l & 15, lk = l >> 4;
  const int bb = blockIdx.x & 7, gg = blockIdx.x >> 3;
  const int b0 = bb * 16;

  { const short8* WoutP = (const short8*)(wsu + 655360);
    ((short8*)wout_lds)[tid] = WoutP[gg * 512 + tid]; }

  const float bo_ = bout[16 * gg + ln];

  // wave w owns gate g = w>>1, sub-tiles s0, s0+1 of this block's 64 units
  const int g = w >> 1, s0 = (w & 1) * 2;
  const int cg0 = g * 16 + 4 * gg + s0;  // global 16-col tile index
  const int lc0 = g * 4 + s0;            // local gbuf tile index

  // thread -> (row rr, unit pair pp): owns units u0 = 2*pp, u0+1 of row rr
  const int rr = tid >> 5, pp = tid & 31;
  const int u0 = 2 * pp;

  // consumer: 3 peer words at (rr, pp); producer: own word at (rr, pp)
  int wiA, wiB, wiC, goA, goB, goC;
  {
    int gi[3], n = 0;
#pragma unroll
    for (int x = 0; x < 4; x++) if (x != gg) gi[n++] = x;
    wiA = ((bb * 16 + rr) * 4 + gi[0]) * 32 + pp; goA = 64 * gi[0];
    wiB = ((bb * 16 + rr) * 4 + gi[1]) * 32 + pp; goB = 64 * gi[1];
    wiC = ((bb * 16 + rr) * 4 + gi[2]) * 32 + pp; goC = 64 * gi[2];
  }
  const int pidx = ((bb * 16 + rr) * 4 + gg) * 32 + pp;

  float creg[2] = {0.f, 0.f};
  unsigned hreg = 0u;  // own h pair (2 bf16), staged into zb next step

  const int xr0 = tid >> 5, xf0 = (tid & 31) * 2;
  float xv0 = xg[(size_t)(b0 + xr0) * TT * FF + xf0];
  float xv1 = xg[(size_t)(b0 + xr0) * TT * FF + xf0 + 1];

  __syncthreads();  // wout_lds visible

  for (int ph = 0; ph < 2; ++ph) {
    const short8* WhhP = (const short8*)(wsu + (ph ? 327680 : 0));
    const short8* WihP = (const short8*)(wsu + (ph ? 589824 : 262144));
    const float* bias = ph ? b_d : b_e;

    short8 rW0[10], rW1[10];  // ks0..7 = Whh, ks8..9 = Wih — register-resident
#pragma unroll
    for (int ks = 0; ks < 8; ks++) {
      rW0[ks] = WhhP[(cg0 * 8 + ks) * 64 + l];
      rW1[ks] = WhhP[((cg0 + 1) * 8 + ks) * 64 + l];
    }
    rW0[8] = WihP[(cg0 * 2 + 0) * 64 + l];
    rW0[9] = WihP[(cg0 * 2 + 1) * 64 + l];
    rW1[8] = WihP[((cg0 + 1) * 2 + 0) * 64 + l];
    rW1[9] = WihP[((cg0 + 1) * 2 + 1) * 64 + l];

    float bact[4][2];
#pragma unroll
    for (int g2 = 0; g2 < 4; g2++) {
      bact[g2][0] = bias[g2 * 256 + 64 * gg + u0];
      bact[g2][1] = bias[g2 * 256 + 64 * gg + u0 + 1];
    }

#pragma unroll 1
    for (int ti = 0; ti < TT; ++ti) {
      const int it = ph * TT + ti;
      const int t = ph ? (TT - 1 - ti) : ti;

      // pin resident weights EVERY iteration: asm "writes" them, so reloading
      // from memory would be a miscompile -> allocator must keep them in VGPRs
#pragma unroll
      for (int ks = 0; ks < 10; ks++) { pin8(rW0[ks]); pin8(rW1[ks]); }

      // stage x(t) and own h pair into zb
      *(unsigned*)&zb[xr0][HH + xf0] = (unsigned)f2b(xv0) | ((unsigned)f2b(xv1) << 16);
      *(unsigned*)&zb[rr][64 * gg + u0] = hreg;

      // spin on 3 peers' tagged words (fence-free), unpack into zb
      {
        const u64t* base = hb + (size_t)(it & 1) * 16384;
        u64t vA = 0, vB = 0, vC = 0;
        bool dA = false, dB = false, dC = false;
        do {
          if (!dA) { vA = __hip_atomic_load(base + wiA, __ATOMIC_RELAXED, __HIP_MEMORY_SCOPE_AGENT);
                     dA = ((unsigned)vA == (unsigned)it); }
          if (!dB) { vB = __hip_atomic_load(base + wiB, __ATOMIC_RELAXED, __HIP_MEMORY_SCOPE_AGENT);
                     dB = ((unsigned)vB == (unsigned)it); }
          if (!dC) { vC = __hip_atomic_load(base + wiC, __ATOMIC_RELAXED, __HIP_MEMORY_SCOPE_AGENT);
                     dC = ((unsigned)vC == (unsigned)it); }
        } while (!(dA && dB && dC));
        *(unsigned*)&zb[rr][goA + u0] = (unsigned)(vA >> 32);
        *(unsigned*)&zb[rr][goB + u0] = (unsigned)(vB >> 32);
        *(unsigned*)&zb[rr][goC + u0] = (unsigned)(vC >> 32);
      }
      __syncthreads();  // B1: full z assembled

      short8 afr[10];
#pragma unroll
      for (int ks = 0; ks < 10; ks++) afr[ks] = *(const short8*)&zb[ln][ks * 32 + lk * 8];

      {  // prefetch next x
        int it2 = it + 1; if (it2 >= 2 * TT) it2 = 0;
        int t2 = (it2 < TT) ? it2 : (2 * TT - 1 - it2);
        const float* px = &xg[((size_t)(b0 + xr0) * TT + t2) * FF + xf0];
        xv0 = px[0]; xv1 = px[1];
      }

      f32x4 acc0 = {0.f, 0.f, 0.f, 0.f}, acc1 = {0.f, 0.f, 0.f, 0.f};
#pragma unroll
      for (int ks = 0; ks < 10; ks++) {
        acc0 = __builtin_amdgcn_mfma_f32_16x16x32_bf16(afr[ks], rW0[ks], acc0, 0, 0, 0);
        acc1 = __builtin_amdgcn_mfma_f32_16x16x32_bf16(afr[ks], rW1[ks], acc1, 0, 0, 0);
      }

      // decoder output (wave 7): out[:,t] = h(it) @ Wout^T + bout, feats 16gg..16gg+16
      if (ph == 1 && w == 7) {
        f32x4 oa = {0.f, 0.f, 0.f, 0.f};
#pragma unroll
        for (int ks = 0; ks < 8; ks++)
          oa = __builtin_amdgcn_mfma_f32_16x16x32_bf16(afr[ks], ((const short8*)wout_lds)[ks * 64 + l], oa, 0, 0, 0);
#pragma unroll
        for (int r = 0; r < 4; r++)
          out[((size_t)(b0 + lk * 4 + r) * TT + t) * FF + 16 * gg + ln] = oa[r] + bo_;
      }

#pragma unroll
      for (int j = 0; j < 4; j++) {
        gbuf[lc0][lk * 4 + j][ln] = acc0[j];
        gbuf[lc0 + 1][lk * 4 + j][ln] = acc1[j];
      }
      __syncthreads();  // B3: gbuf ready (also orders zb reads vs next-step writes)

      // activation for units (rr, u0), (rr, u0+1); publish straight from registers
      unsigned short hu[2];
#pragma unroll
      for (int e = 0; e < 2; e++) {
        const int u = u0 + e, ss = u >> 4, uc = u & 15;
        float gi = gbuf[0 + ss][rr][uc] + bact[0][e];
        float gf = gbuf[4 + ss][rr][uc] + bact[1][e];
        float gG = gbuf[8 + ss][rr][uc] + bact[2][e];
        float go = gbuf[12 + ss][rr][uc] + bact[3][e];
        float si = 1.f / (1.f + __expf(-gi));
        float sf = 1.f / (1.f + __expf(-gf));
        float tg = 1.f - 2.f / (__expf(2.f * gG) + 1.f);
        float so = 1.f / (1.f + __expf(-go));
        float cn = sf * creg[e] + si * tg;
        creg[e] = cn;
        float hn = so * (1.f - 2.f / (__expf(2.f * cn) + 1.f));
        hu[e] = f2b(hn);
      }
      hreg = (unsigned)hu[0] | ((unsigned)hu[1] << 16);

      // publish own h(it+1) pair: [tag32 | h0 | h1], relaxed agent atomic, no fence
      {
        u64t word = (u64t)(unsigned)(it + 1) | ((u64t)hreg << 32);
        __hip_atomic_store(hb + (size_t)((it + 1) & 1) * 16384 + pidx, word,
                           __ATOMIC_RELAXED, __HIP_MEMORY_SCOPE_AGENT);
      }
    }
  }
}

extern "C" void kernel_launch(void* const* d_in, const int* in_sizes, int n_in,
                              void* d_out, int out_size, void* d_ws, size_t ws_size,
                              hipStream_t stream) {
  const float* ts    = (const float*)d_in[0];
  const float* Wih_e = (const float*)d_in[1];
  const float* Whh_e = (const float*)d_in[2];
  const float* b_e   = (const float*)d_in[3];
  const float* Wih_d = (const float*)d_in[4];
  const float* Whh_d = (const float*)d_in[5];
  const float* b_d   = (const float*)d_in[6];
  const float* Wout  = (const float*)d_in[7];
  const float* bout  = (const float*)d_in[8];
  unsigned short* ws = (unsigned short*)d_ws;
  float* out = (float*)d_out;
  u64t* hb = (u64t*)((char*)d_ws + WS_HB_B);

  prep_kernel<<<328, 256, 0, stream>>>(Wih_e, Whh_e, Wih_d, Whh_d, Wout, ws);
  init_hb<<<64, 512, 0, stream>>>(hb);
  lstm_kernel<<<32, 512, 0, stream>>>(ts, b_e, b_d, bout, ws, out, hb);
}

// Round 7
// 9403.291 us; speedup vs baseline: 4.6622x; 1.0192x over previous
//
#include <hip/hip_runtime.h>

#define TT 2048
#define FF 64
#define HH 256

typedef short short8 __attribute__((ext_vector_type(8)));
typedef float f32x4 __attribute__((ext_vector_type(4)));
typedef unsigned long long u64t;

// ws layout (bytes):
//  [0)        packed bf16 weights (ushorts): WhhE@0 WihE@262144 WhhD@327680 WihD@589824 WoutP@655360
//  [1343488)  hb: [2 par][8 bb][16 r][4 g][32 pair] u64 tagged h-words = 32768*8 = 262144 B
#define WS_HB_B 1343488

__device__ inline unsigned short f2b(float f) {
  unsigned int u = __builtin_bit_cast(unsigned int, f);
  u += 0x7fffu + ((u >> 16) & 1u);
  return (unsigned short)(u >> 16);
}
__device__ inline void pin8(short8 &v) { asm volatile("" : "+v"(v)); }

// pack fragment-linear bf16 weights into ws
__global__ void prep_kernel(const float* __restrict__ Wih_e, const float* __restrict__ Whh_e,
                            const float* __restrict__ Wih_d, const float* __restrict__ Whh_d,
                            const float* __restrict__ Wout, unsigned short* __restrict__ ws) {
  int idx = blockIdx.x * blockDim.x + threadIdx.x;
  if (idx >= 83968) return;
  const float* src; unsigned short* dst; int q, kdim;
  if (idx < 32768)      { q = idx;         src = Whh_e; dst = ws + 0      + q * 8; kdim = HH; }
  else if (idx < 40960) { q = idx - 32768; src = Wih_e; dst = ws + 262144 + q * 8; kdim = FF; }
  else if (idx < 73728) { q = idx - 40960; src = Whh_d; dst = ws + 327680 + q * 8; kdim = HH; }
  else if (idx < 81920) { q = idx - 73728; src = Wih_d; dst = ws + 589824 + q * 8; kdim = FF; }
  else                  { q = idx - 81920; src = Wout;  dst = ws + 655360 + q * 8; kdim = HH; }
  int ksPerTile = (kdim == HH) ? 8 : 2;
  int per = ksPerTile * 64;
  int tile = q / per, rem = q % per;
  int ks = rem / 64, l = rem % 64;
  int col = tile * 16 + (l & 15);
  int k0 = ks * 32 + (l >> 4) * 8;
#pragma unroll
  for (int e = 0; e < 8; e++) dst[e] = f2b(src[col * kdim + k0 + e]);
}

// zero tagged exchange buffer each launch (tag 0 == "h(0) = 0" for free)
__global__ void init_hb(u64t* __restrict__ hb) {
  int i = blockIdx.x * blockDim.x + threadIdx.x;
  if (i < 32768) hb[i] = 0ull;
}

// 32 blocks: bb = bid&7 (batch group -> all 4 peers share an XCD under %8 round-robin),
// gg = bid>>3 (hidden quarter, 64 units). All gate weights register-resident (pinned
// EVERY iteration so the compiler cannot rematerialize). Fence-free tagged h exchange.
__global__ __launch_bounds__(512, 1) void lstm_kernel(
    const float* __restrict__ xg, const float* __restrict__ b_e,
    const float* __restrict__ b_d, const float* __restrict__ bout,
    const unsigned short* __restrict__ wsu, float* __restrict__ out,
    u64t* __restrict__ hb) {
  __shared__ unsigned short zb[16][328];     // z = [h(256)|x(64)] bf16
  __shared__ float gbuf[16][16][17];         // 16 local gate tiles, padded rows
  __shared__ unsigned short wout_lds[4096];  // Wout tile gg: [8 ks][64 lanes][8]

  const int tid = threadIdx.x;
  const int l = tid & 63, w = tid >> 6;
  const int ln = l & 15, lk = l >> 4;
  const int bb = blockIdx.x & 7, gg = blockIdx.x >> 3;
  const int b0 = bb * 16;

  { const short8* WoutP = (const short8*)(wsu + 655360);
    ((short8*)wout_lds)[tid] = WoutP[gg * 512 + tid]; }

  const float bo_ = bout[16 * gg + ln];

  // wave w owns gate g = w>>1, sub-tiles s0, s0+1 of this block's 64 units
  const int g = w >> 1, s0 = (w & 1) * 2;
  const int cg0 = g * 16 + 4 * gg + s0;  // global 16-col tile index
  const int lc0 = g * 4 + s0;            // local gbuf tile index

  // thread -> (row rr, unit pair pp): owns units u0 = 2*pp, u0+1 of row rr
  const int rr = tid >> 5, pp = tid & 31;
  const int u0 = 2 * pp;

  // consumer: 3 peer words at (rr, pp); producer: own word at (rr, pp)
  int wiA, wiB, wiC, goA, goB, goC;
  {
    int gi[3], n = 0;
#pragma unroll
    for (int x = 0; x < 4; x++) if (x != gg) gi[n++] = x;
    wiA = ((bb * 16 + rr) * 4 + gi[0]) * 32 + pp; goA = 64 * gi[0];
    wiB = ((bb * 16 + rr) * 4 + gi[1]) * 32 + pp; goB = 64 * gi[1];
    wiC = ((bb * 16 + rr) * 4 + gi[2]) * 32 + pp; goC = 64 * gi[2];
  }
  const int pidx = ((bb * 16 + rr) * 4 + gg) * 32 + pp;

  float creg[2] = {0.f, 0.f};
  unsigned hreg = 0u;  // own h pair (2 bf16), staged into zb next step

  const int xr0 = tid >> 5, xf0 = (tid & 31) * 2;
  float xv0 = xg[(size_t)(b0 + xr0) * TT * FF + xf0];
  float xv1 = xg[(size_t)(b0 + xr0) * TT * FF + xf0 + 1];

  __syncthreads();  // wout_lds visible

  for (int ph = 0; ph < 2; ++ph) {
    const short8* WhhP = (const short8*)(wsu + (ph ? 327680 : 0));
    const short8* WihP = (const short8*)(wsu + (ph ? 589824 : 262144));
    const float* bias = ph ? b_d : b_e;

    short8 rW0[10], rW1[10];  // ks0..7 = Whh, ks8..9 = Wih — register-resident
#pragma unroll
    for (int ks = 0; ks < 8; ks++) {
      rW0[ks] = WhhP[(cg0 * 8 + ks) * 64 + l];
      rW1[ks] = WhhP[((cg0 + 1) * 8 + ks) * 64 + l];
    }
    rW0[8] = WihP[(cg0 * 2 + 0) * 64 + l];
    rW0[9] = WihP[(cg0 * 2 + 1) * 64 + l];
    rW1[8] = WihP[((cg0 + 1) * 2 + 0) * 64 + l];
    rW1[9] = WihP[((cg0 + 1) * 2 + 1) * 64 + l];

    float bact[4][2];
#pragma unroll
    for (int g2 = 0; g2 < 4; g2++) {
      bact[g2][0] = bias[g2 * 256 + 64 * gg + u0];
      bact[g2][1] = bias[g2 * 256 + 64 * gg + u0 + 1];
    }

#pragma unroll 1
    for (int ti = 0; ti < TT; ++ti) {
      const int it = ph * TT + ti;
      const int t = ph ? (TT - 1 - ti) : ti;

      // pin resident weights EVERY iteration: asm "writes" them, so reloading
      // from memory would be a miscompile -> allocator must keep them in VGPRs
#pragma unroll
      for (int ks = 0; ks < 10; ks++) { pin8(rW0[ks]); pin8(rW1[ks]); }

      // stage x(t) and own h pair into zb
      *(unsigned*)&zb[xr0][HH + xf0] = (unsigned)f2b(xv0) | ((unsigned)f2b(xv1) << 16);
      *(unsigned*)&zb[rr][64 * gg + u0] = hreg;

      // spin on 3 peers' tagged words (fence-free), unpack into zb
      {
        const u64t* base = hb + (size_t)(it & 1) * 16384;
        u64t vA = 0, vB = 0, vC = 0;
        bool dA = false, dB = false, dC = false;
        do {
          if (!dA) { vA = __hip_atomic_load(base + wiA, __ATOMIC_RELAXED, __HIP_MEMORY_SCOPE_AGENT);
                     dA = ((unsigned)vA == (unsigned)it); }
          if (!dB) { vB = __hip_atomic_load(base + wiB, __ATOMIC_RELAXED, __HIP_MEMORY_SCOPE_AGENT);
                     dB = ((unsigned)vB == (unsigned)it); }
          if (!dC) { vC = __hip_atomic_load(base + wiC, __ATOMIC_RELAXED, __HIP_MEMORY_SCOPE_AGENT);
                     dC = ((unsigned)vC == (unsigned)it); }
        } while (!(dA && dB && dC));
        *(unsigned*)&zb[rr][goA + u0] = (unsigned)(vA >> 32);
        *(unsigned*)&zb[rr][goB + u0] = (unsigned)(vB >> 32);
        *(unsigned*)&zb[rr][goC + u0] = (unsigned)(vC >> 32);
      }
      __syncthreads();  // B1: full z assembled

      short8 afr[10];
#pragma unroll
      for (int ks = 0; ks < 10; ks++) afr[ks] = *(const short8*)&zb[ln][ks * 32 + lk * 8];

      {  // prefetch next x
        int it2 = it + 1; if (it2 >= 2 * TT) it2 = 0;
        int t2 = (it2 < TT) ? it2 : (2 * TT - 1 - it2);
        const float* px = &xg[((size_t)(b0 + xr0) * TT + t2) * FF + xf0];
        xv0 = px[0]; xv1 = px[1];
      }

      f32x4 acc0 = {0.f, 0.f, 0.f, 0.f}, acc1 = {0.f, 0.f, 0.f, 0.f};
#pragma unroll
      for (int ks = 0; ks < 10; ks++) {
        acc0 = __builtin_amdgcn_mfma_f32_16x16x32_bf16(afr[ks], rW0[ks], acc0, 0, 0, 0);
        acc1 = __builtin_amdgcn_mfma_f32_16x16x32_bf16(afr[ks], rW1[ks], acc1, 0, 0, 0);
      }

      // decoder output (wave 7): out[:,t] = h(it) @ Wout^T + bout, feats 16gg..16gg+16
      if (ph == 1 && w == 7) {
        f32x4 oa = {0.f, 0.f, 0.f, 0.f};
#pragma unroll
        for (int ks = 0; ks < 8; ks++)
          oa = __builtin_amdgcn_mfma_f32_16x16x32_bf16(afr[ks], ((const short8*)wout_lds)[ks * 64 + l], oa, 0, 0, 0);
#pragma unroll
        for (int r = 0; r < 4; r++)
          out[((size_t)(b0 + lk * 4 + r) * TT + t) * FF + 16 * gg + ln] = oa[r] + bo_;
      }

#pragma unroll
      for (int j = 0; j < 4; j++) {
        gbuf[lc0][lk * 4 + j][ln] = acc0[j];
        gbuf[lc0 + 1][lk * 4 + j][ln] = acc1[j];
      }
      __syncthreads();  // B3: gbuf ready (also orders zb reads vs next-step writes)

      // activation for units (rr, u0), (rr, u0+1); publish straight from registers
      unsigned short hu[2];
#pragma unroll
      for (int e = 0; e < 2; e++) {
        const int u = u0 + e, ss = u >> 4, uc = u & 15;
        float gi = gbuf[0 + ss][rr][uc] + bact[0][e];
        float gf = gbuf[4 + ss][rr][uc] + bact[1][e];
        float gG = gbuf[8 + ss][rr][uc] + bact[2][e];
        float go = gbuf[12 + ss][rr][uc] + bact[3][e];
        float si = 1.f / (1.f + __expf(-gi));
        float sf = 1.f / (1.f + __expf(-gf));
        float tg = 1.f - 2.f / (__expf(2.f * gG) + 1.f);
        float so = 1.f / (1.f + __expf(-go));
        float cn = sf * creg[e] + si * tg;
        creg[e] = cn;
        float hn = so * (1.f - 2.f / (__expf(2.f * cn) + 1.f));
        hu[e] = f2b(hn);
      }
      hreg = (unsigned)hu[0] | ((unsigned)hu[1] << 16);

      // publish own h(it+1) pair: [tag32 | h0 | h1], relaxed agent atomic, no fence
      {
        u64t word = (u64t)(unsigned)(it + 1) | ((u64t)hreg << 32);
        __hip_atomic_store(hb + (size_t)((it + 1) & 1) * 16384 + pidx, word,
                           __ATOMIC_RELAXED, __HIP_MEMORY_SCOPE_AGENT);
      }
    }
  }
}

extern "C" void kernel_launch(void* const* d_in, const int* in_sizes, int n_in,
                              void* d_out, int out_size, void* d_ws, size_t ws_size,
                              hipStream_t stream) {
  const float* ts    = (const float*)d_in[0];
  const float* Wih_e = (const float*)d_in[1];
  const float* Whh_e = (const float*)d_in[2];
  const float* b_e   = (const float*)d_in[3];
  const float* Wih_d = (const float*)d_in[4];
  const float* Whh_d = (const float*)d_in[5];
  const float* b_d   = (const float*)d_in[6];
  const float* Wout  = (const float*)d_in[7];
  const float* bout  = (const float*)d_in[8];
  unsigned short* ws = (unsigned short*)d_ws;
  float* out = (float*)d_out;
  u64t* hb = (u64t*)((char*)d_ws + WS_HB_B);

  prep_kernel<<<328, 256, 0, stream>>>(Wih_e, Whh_e, Wih_d, Whh_d, Wout, ws);
  init_hb<<<64, 512, 0, stream>>>(hb);
  lstm_kernel<<<32, 512, 0, stream>>>(ts, b_e, b_d, bout, ws, out, hb);
}